// Round 2
// baseline (7475.894 us; speedup 1.0000x reference)
//
#include <hip/hip_runtime.h>
#include <math.h>

#define D_MODEL 1024
#define D_STATE 16
#define D_CONV  4
#define D_INNER 2048
#define DT_RANK 64
#define B_SZ    2
#define SEQ     4096
#define BL      (B_SZ*SEQ)   // 8192 rows

__device__ __forceinline__ float siluf(float v) { return v / (1.f + __expf(-v)); }

__global__ __launch_bounds__(256) void fill_kernel(float* p, int n, float v) {
  int i = blockIdx.x * 256 + threadIdx.x;
  if (i < n) p[i] = v;
}

// C[M,N] = A[M,K] @ B[N,K]^T    (B row-major [N][K])
// EPI==0: plain store to C0[m*N+n]
// EPI==1: split: n < D_INNER -> C0 (x_inner), else C1 (silu(z))
template <int EPI>
__global__ __launch_bounds__(256) void gemm_att(const float* __restrict__ A,
                                                const float* __restrict__ B,
                                                float* __restrict__ C0,
                                                float* __restrict__ C1,
                                                int M, int N, int K) {
  __shared__ float As[16][65];
  __shared__ float Bs[16][65];
  const int nblk = N >> 6;
  const int bx = blockIdx.x % nblk;
  const int by = blockIdx.x / nblk;
  const int m0 = by << 6, n0 = bx << 6;
  const int tid = threadIdx.x;
  const int tx = tid & 15, ty = tid >> 4;

  float acc[4][4] = {};
  for (int k0 = 0; k0 < K; k0 += 16) {
#pragma unroll
    for (int j = 0; j < 4; ++j) {
      int i = tid + j * 256;
      int r = i >> 4, c = i & 15;
      As[c][r] = A[(size_t)(m0 + r) * K + k0 + c];
      Bs[c][r] = B[(size_t)(n0 + r) * K + k0 + c];
    }
    __syncthreads();
#pragma unroll
    for (int k = 0; k < 16; ++k) {
      float a[4], b[4];
#pragma unroll
      for (int i = 0; i < 4; ++i) a[i] = As[k][ty * 4 + i];
#pragma unroll
      for (int i = 0; i < 4; ++i) b[i] = Bs[k][tx * 4 + i];
#pragma unroll
      for (int i = 0; i < 4; ++i)
#pragma unroll
        for (int j = 0; j < 4; ++j) acc[i][j] += a[i] * b[j];
    }
    __syncthreads();
  }

#pragma unroll
  for (int i = 0; i < 4; ++i) {
#pragma unroll
    for (int j = 0; j < 4; ++j) {
      int m = m0 + ty * 4 + i;
      int n = n0 + tx * 4 + j;
      float v = acc[i][j];
      if (EPI == 0) {
        C0[(size_t)m * N + n] = v;
      } else {
        if (n < D_INNER)
          C0[(size_t)m * D_INNER + n] = v;
        else
          C1[(size_t)m * D_INNER + (n - D_INNER)] = siluf(v);
      }
    }
  }
}

// x_dbl[BL,96] = x_conv[BL,2048] @ W_x[96,2048]^T, with x_conv computed
// on the fly from x_inner (causal depthwise conv + bias + silu).
__global__ __launch_bounds__(256) void gemm_xdbl_conv(const float* __restrict__ xin_,
                                                      const float* __restrict__ cw,
                                                      const float* __restrict__ cb,
                                                      const float* __restrict__ Bw,
                                                      float* __restrict__ C) {
  __shared__ float As[32][33];
  __shared__ float Bs[96][33];
  const int m0 = blockIdx.x * 32;
  const int tid = threadIdx.x;
  const int tx = tid & 15, ty = tid >> 4;   // tx: 6 cols each, ty: 2 rows each
  float acc[2][6] = {};
  for (int k0 = 0; k0 < D_INNER; k0 += 32) {
#pragma unroll
    for (int j = 0; j < 4; ++j) {
      int i = tid + j * 256;
      int r = i >> 5, c = i & 31;
      int m = m0 + r;
      int d = k0 + c;
      int t = m & (SEQ - 1);
      float a = cb[d];
#pragma unroll
      for (int kk = 0; kk < D_CONV; ++kk) {
        int tt = t - (D_CONV - 1) + kk;
        if (tt >= 0) a += xin_[(size_t)(m - (D_CONV - 1) + kk) * D_INNER + d] * cw[d * D_CONV + kk];
      }
      As[r][c] = siluf(a);
    }
#pragma unroll
    for (int j = 0; j < 12; ++j) {
      int i = tid + j * 256;
      int r = i >> 5, c = i & 31;
      Bs[r][c] = Bw[(size_t)r * D_INNER + k0 + c];
    }
    __syncthreads();
#pragma unroll
    for (int k = 0; k < 32; ++k) {
#pragma unroll
      for (int rr = 0; rr < 2; ++rr) {
        float a = As[ty * 2 + rr][k];
#pragma unroll
        for (int j = 0; j < 6; ++j) acc[rr][j] += a * Bs[tx * 6 + j][k];
      }
    }
    __syncthreads();
  }
#pragma unroll
  for (int rr = 0; rr < 2; ++rr)
#pragma unroll
    for (int j = 0; j < 6; ++j)
      C[(size_t)(m0 + ty * 2 + rr) * 96 + tx * 6 + j] = acc[rr][j];
}

// selective scan with fused conv (rolling window) and fused dt projection;
// writes y*silu(z) in-place over zs
__global__ __launch_bounds__(256) void scan_fused(const float* __restrict__ xin_,
                                                  const float* __restrict__ xdbl,
                                                  const float* __restrict__ cw,
                                                  const float* __restrict__ cb,
                                                  const float* __restrict__ Wdt,
                                                  const float* __restrict__ bdt,
                                                  const float* __restrict__ Alog,
                                                  const float* __restrict__ Dp,
                                                  float* __restrict__ zs) {
  const int tid = threadIdx.x;
  const int n = tid & 15;
  const int cwi = tid >> 4;                // 0..15 channel within block
  const int ch = blockIdx.x * 16 + cwi;    // 0..4095
  const int b = ch >> 11;
  const int d = ch & (D_INNER - 1);
  const float A = -__expf(Alog[d * D_STATE + n]);
  const float Dv = Dp[d];
  const float w0 = cw[d * D_CONV + 0], w1 = cw[d * D_CONV + 1];
  const float w2 = cw[d * D_CONV + 2], w3 = cw[d * D_CONV + 3];
  const float cbv = cb[d];
  const float bdtv = bdt[d];
  const float wdt0 = Wdt[(size_t)d * DT_RANK + n];
  const float wdt1 = Wdt[(size_t)d * DT_RANK + n + 16];
  const float wdt2 = Wdt[(size_t)d * DT_RANK + n + 32];
  const float wdt3 = Wdt[(size_t)d * DT_RANK + n + 48];

  float xw0 = 0.f, xw1 = 0.f, xw2 = 0.f;   // x_inner[t-3..t-1], zero-pad before start
  float h = 0.f;
  const size_t rowbase = (size_t)b * SEQ;
  for (int t = 0; t < SEQ; ++t) {
    const size_t row = rowbase + t;
    const float xw3 = xin_[row * D_INNER + d];
    const float* xr = xdbl + row * 96;
    // dt = softplus(b_dt + dt_low . W_dt[d,:])
    float p = xr[n] * wdt0 + xr[n + 16] * wdt1 + xr[n + 32] * wdt2 + xr[n + 48] * wdt3;
    p += __shfl_xor(p, 1, 16);
    p += __shfl_xor(p, 2, 16);
    p += __shfl_xor(p, 4, 16);
    p += __shfl_xor(p, 8, 16);
    const float v = p + bdtv;
    const float dtv = (v > 20.f) ? v : log1pf(__expf(v));
    // conv + silu on the fly
    float xc = cbv + w0 * xw0 + w1 * xw1 + w2 * xw2 + w3 * xw3;
    xc = siluf(xc);
    const float Bv = xr[DT_RANK + n];
    const float Cv = xr[DT_RANK + D_STATE + n];
    const float ab = __expf(dtv * A);
    h = ab * h + (dtv * xc) * Bv;
    float contrib = h * Cv;
    contrib += __shfl_xor(contrib, 1, 16);
    contrib += __shfl_xor(contrib, 2, 16);
    contrib += __shfl_xor(contrib, 4, 16);
    contrib += __shfl_xor(contrib, 8, 16);
    if (n == 0) {
      const size_t idx = row * D_INNER + d;
      zs[idx] = (contrib + Dv * xc) * zs[idx];
    }
    xw0 = xw1; xw1 = xw2; xw2 = xw3;
  }
}

extern "C" void kernel_launch(void* const* d_in, const int* in_sizes, int n_in,
                              void* d_out, int out_size, void* d_ws, size_t ws_size,
                              hipStream_t stream) {
  const float* x      = (const float*)d_in[0];
  const float* W_in   = (const float*)d_in[1];
  const float* conv_w = (const float*)d_in[2];
  const float* conv_b = (const float*)d_in[3];
  const float* W_x    = (const float*)d_in[4];
  const float* W_dt   = (const float*)d_in[5];
  const float* b_dt   = (const float*)d_in[6];
  const float* A_log  = (const float*)d_in[7];
  const float* Dp     = (const float*)d_in[8];
  const float* W_out  = (const float*)d_in[9];
  float* out = (float*)d_out;

  const size_t NE = (size_t)BL * D_INNER;        // 16.8M
  const size_t need = (2 * NE + (size_t)BL * 96) * sizeof(float);  // ~137 MB
  if (ws_size < need) {
    // diagnostic sentinel: distinguishes "ws too small" from "nothing ran"
    fill_kernel<<<dim3((out_size + 255) / 256), 256, 0, stream>>>(out, out_size, 1.0e9f);
    return;
  }

  float* ws      = (float*)d_ws;
  float* x_inner = ws;            // NE
  float* z_silu  = x_inner + NE;  // NE
  float* x_dbl   = z_silu + NE;   // BL*96

  // 1) xz projection: [8192,4096] = x @ W_in^T ; split into x_inner / silu(z)
  gemm_att<1><<<dim3((4096 / 64) * (BL / 64)), 256, 0, stream>>>(
      x, W_in, x_inner, z_silu, BL, 2 * D_INNER, D_MODEL);

  // 2) x_dbl = conv_silu(x_inner) @ W_x^T   (conv fused into A-tile load)
  gemm_xdbl_conv<<<dim3(BL / 32), 256, 0, stream>>>(
      x_inner, conv_w, conv_b, W_x, x_dbl);

  // 3) selective scan (conv + dt fused); y * silu(z) -> z_silu (in place)
  scan_fused<<<dim3((B_SZ * D_INNER) / 16), 256, 0, stream>>>(
      x_inner, x_dbl, conv_w, conv_b, W_dt, b_dt, A_log, Dp, z_silu);

  // 4) out = (y * silu(z)) @ W_out^T
  gemm_att<0><<<dim3((D_MODEL / 64) * (BL / 64)), 256, 0, stream>>>(
      z_silu, W_out, out, nullptr, BL, D_MODEL, D_INNER);
}

// Round 3
// 4307.859 us; speedup vs baseline: 1.7354x; 1.7354x over previous
//
#include <hip/hip_runtime.h>
#include <math.h>

#define D_MODEL 1024
#define D_STATE 16
#define D_CONV  4
#define D_INNER 2048
#define DT_RANK 64
#define B_SZ    2
#define SEQ     4096
#define BL      (B_SZ*SEQ)   // 8192 rows
#define NCH     64           // time chunks
#define CL      (SEQ/NCH)    // 64 steps per chunk
#define NCHAN   (B_SZ*D_INNER)  // 4096 scan channels

__device__ __forceinline__ float siluf(float v) { return v / (1.f + __expf(-v)); }

__global__ __launch_bounds__(256) void fill_kernel(float* p, int n, float v) {
  int i = blockIdx.x * 256 + threadIdx.x;
  if (i < n) p[i] = v;
}

// C[M,N] = A[M,K] @ B[N,K]^T    (B row-major [N][K])
// EPI==0: plain store to C0[m*N+n]
// EPI==1: split: n < D_INNER -> C0 (x_inner), else C1 (silu(z))
template <int EPI>
__global__ __launch_bounds__(256) void gemm_att(const float* __restrict__ A,
                                                const float* __restrict__ B,
                                                float* __restrict__ C0,
                                                float* __restrict__ C1,
                                                int M, int N, int K) {
  __shared__ float As[16][65];
  __shared__ float Bs[16][65];
  const int nblk = N >> 6;
  const int bx = blockIdx.x % nblk;
  const int by = blockIdx.x / nblk;
  const int m0 = by << 6, n0 = bx << 6;
  const int tid = threadIdx.x;
  const int tx = tid & 15, ty = tid >> 4;

  float acc[4][4] = {};
  for (int k0 = 0; k0 < K; k0 += 16) {
#pragma unroll
    for (int j = 0; j < 4; ++j) {
      int i = tid + j * 256;
      int r = i >> 4, c = i & 15;
      As[c][r] = A[(size_t)(m0 + r) * K + k0 + c];
      Bs[c][r] = B[(size_t)(n0 + r) * K + k0 + c];
    }
    __syncthreads();
#pragma unroll
    for (int k = 0; k < 16; ++k) {
      float a[4], b[4];
#pragma unroll
      for (int i = 0; i < 4; ++i) a[i] = As[k][ty * 4 + i];
#pragma unroll
      for (int i = 0; i < 4; ++i) b[i] = Bs[k][tx * 4 + i];
#pragma unroll
      for (int i = 0; i < 4; ++i)
#pragma unroll
        for (int j = 0; j < 4; ++j) acc[i][j] += a[i] * b[j];
    }
    __syncthreads();
  }

#pragma unroll
  for (int i = 0; i < 4; ++i) {
#pragma unroll
    for (int j = 0; j < 4; ++j) {
      int m = m0 + ty * 4 + i;
      int n = n0 + tx * 4 + j;
      float v = acc[i][j];
      if (EPI == 0) {
        C0[(size_t)m * N + n] = v;
      } else {
        if (n < D_INNER)
          C0[(size_t)m * D_INNER + n] = v;
        else
          C1[(size_t)m * D_INNER + (n - D_INNER)] = siluf(v);
      }
    }
  }
}

// x_dbl[BL,96] = conv_silu(x_inner)[BL,2048] @ W_x[96,2048]^T (conv fused)
__global__ __launch_bounds__(256) void gemm_xdbl_conv(const float* __restrict__ xin_,
                                                      const float* __restrict__ cw,
                                                      const float* __restrict__ cb,
                                                      const float* __restrict__ Bw,
                                                      float* __restrict__ C) {
  __shared__ float As[32][33];
  __shared__ float Bs[96][33];
  const int m0 = blockIdx.x * 32;
  const int tid = threadIdx.x;
  const int tx = tid & 15, ty = tid >> 4;
  float acc[2][6] = {};
  for (int k0 = 0; k0 < D_INNER; k0 += 32) {
#pragma unroll
    for (int j = 0; j < 4; ++j) {
      int i = tid + j * 256;
      int r = i >> 5, c = i & 31;
      int m = m0 + r;
      int d = k0 + c;
      int t = m & (SEQ - 1);
      float a = cb[d];
#pragma unroll
      for (int kk = 0; kk < D_CONV; ++kk) {
        int tt = t - (D_CONV - 1) + kk;
        if (tt >= 0) a += xin_[(size_t)(m - (D_CONV - 1) + kk) * D_INNER + d] * cw[d * D_CONV + kk];
      }
      As[r][c] = siluf(a);
    }
#pragma unroll
    for (int j = 0; j < 12; ++j) {
      int i = tid + j * 256;
      int r = i >> 5, c = i & 31;
      Bs[r][c] = Bw[(size_t)r * D_INNER + k0 + c];
    }
    __syncthreads();
#pragma unroll
    for (int k = 0; k < 32; ++k) {
#pragma unroll
      for (int rr = 0; rr < 2; ++rr) {
        float a = As[ty * 2 + rr][k];
#pragma unroll
        for (int j = 0; j < 6; ++j) acc[rr][j] += a * Bs[tx * 6 + j][k];
      }
    }
    __syncthreads();
  }
#pragma unroll
  for (int rr = 0; rr < 2; ++rr)
#pragma unroll
    for (int j = 0; j < 6; ++j)
      C[(size_t)(m0 + ty * 2 + rr) * 96 + tx * 6 + j] = acc[rr][j];
}

// ---- chunked selective scan ----
// Pass 1: per (chunk, channel): local scan from h=0 -> h_loc_final, dtsum.
__global__ __launch_bounds__(256) void scan_part1(const float* __restrict__ xin_,
                                                  const float* __restrict__ xdbl,
                                                  const float* __restrict__ cw,
                                                  const float* __restrict__ cb,
                                                  const float* __restrict__ Wdt,
                                                  const float* __restrict__ bdt,
                                                  const float* __restrict__ Alog,
                                                  float* __restrict__ hstate,
                                                  float* __restrict__ dtsum) {
  const int tid = threadIdx.x;
  const int n = tid & 15;
  const int g = blockIdx.x & 255;            // channel group 0..255
  const int c = blockIdx.x >> 8;             // chunk 0..63
  const int ch = g * 16 + (tid >> 4);        // 0..4095
  const int b = ch >> 11;
  const int d = ch & (D_INNER - 1);

  const float A = -__expf(Alog[d * D_STATE + n]);
  const float w0 = cw[d * D_CONV + 0], w1 = cw[d * D_CONV + 1];
  const float w2 = cw[d * D_CONV + 2], w3 = cw[d * D_CONV + 3];
  const float cbv = cb[d];
  const float bdtv = bdt[d];
  const float wdt0 = Wdt[(size_t)d * DT_RANK + n];
  const float wdt1 = Wdt[(size_t)d * DT_RANK + n + 16];
  const float wdt2 = Wdt[(size_t)d * DT_RANK + n + 32];
  const float wdt3 = Wdt[(size_t)d * DT_RANK + n + 48];

  const size_t rowbase = (size_t)b * SEQ;
  const int t0 = c * CL;
  float xw0 = 0.f, xw1 = 0.f, xw2 = 0.f;
  if (c > 0) {
    xw0 = xin_[(rowbase + t0 - 3) * D_INNER + d];
    xw1 = xin_[(rowbase + t0 - 2) * D_INNER + d];
    xw2 = xin_[(rowbase + t0 - 1) * D_INNER + d];
  }
  float h = 0.f, ds = 0.f;
  const float* xr = xdbl + (rowbase + t0) * 96;
  for (int t = 0; t < CL; ++t, xr += 96) {
    const float xw3 = xin_[(rowbase + t0 + t) * D_INNER + d];
    float p = xr[n] * wdt0 + xr[n + 16] * wdt1 + xr[n + 32] * wdt2 + xr[n + 48] * wdt3;
    p += __shfl_xor(p, 1, 16);
    p += __shfl_xor(p, 2, 16);
    p += __shfl_xor(p, 4, 16);
    p += __shfl_xor(p, 8, 16);
    const float v = p + bdtv;
    const float dtv = (v > 20.f) ? v : log1pf(__expf(v));
    float xc = cbv + w0 * xw0 + w1 * xw1 + w2 * xw2 + w3 * xw3;
    xc = siluf(xc);
    const float Bv = xr[DT_RANK + n];
    h = __expf(dtv * A) * h + (dtv * xc) * Bv;
    ds += dtv;
    xw0 = xw1; xw1 = xw2; xw2 = xw3;
  }
  hstate[(size_t)c * (NCHAN * 16) + ch * 16 + n] = h;
  if (n == 0) dtsum[c * NCHAN + ch] = ds;
}

// Pass 2: sequential over chunks; converts h_loc_final -> H_in (in place).
__global__ __launch_bounds__(256) void scan_part2(const float* __restrict__ Alog,
                                                  float* __restrict__ hstate,
                                                  const float* __restrict__ dtsum) {
  const int idx = blockIdx.x * 256 + threadIdx.x;   // 65536 = NCHAN*16
  const int n = idx & 15;
  const int ch = idx >> 4;
  const int d = ch & (D_INNER - 1);
  const float A = -__expf(Alog[d * D_STATE + n]);
  float H = 0.f;
  for (int c = 0; c < NCH; ++c) {
    const size_t off = (size_t)c * (NCHAN * 16) + idx;
    const float hf = hstate[off];
    const float s = dtsum[c * NCHAN + ch];
    const float Ap = __expf(A * s);
    hstate[off] = H;           // H_in for chunk c
    H = Ap * H + hf;
  }
}

// Pass 3: local scan seeded with H_in; y computed; zs *= y (in place).
__global__ __launch_bounds__(256) void scan_part3(const float* __restrict__ xin_,
                                                  const float* __restrict__ xdbl,
                                                  const float* __restrict__ cw,
                                                  const float* __restrict__ cb,
                                                  const float* __restrict__ Wdt,
                                                  const float* __restrict__ bdt,
                                                  const float* __restrict__ Alog,
                                                  const float* __restrict__ Dp,
                                                  const float* __restrict__ hstate,
                                                  float* __restrict__ zs) {
  const int tid = threadIdx.x;
  const int n = tid & 15;
  const int g = blockIdx.x & 255;
  const int c = blockIdx.x >> 8;
  const int ch = g * 16 + (tid >> 4);
  const int b = ch >> 11;
  const int d = ch & (D_INNER - 1);

  const float A = -__expf(Alog[d * D_STATE + n]);
  const float Dv = Dp[d];
  const float w0 = cw[d * D_CONV + 0], w1 = cw[d * D_CONV + 1];
  const float w2 = cw[d * D_CONV + 2], w3 = cw[d * D_CONV + 3];
  const float cbv = cb[d];
  const float bdtv = bdt[d];
  const float wdt0 = Wdt[(size_t)d * DT_RANK + n];
  const float wdt1 = Wdt[(size_t)d * DT_RANK + n + 16];
  const float wdt2 = Wdt[(size_t)d * DT_RANK + n + 32];
  const float wdt3 = Wdt[(size_t)d * DT_RANK + n + 48];

  const size_t rowbase = (size_t)b * SEQ;
  const int t0 = c * CL;
  float xw0 = 0.f, xw1 = 0.f, xw2 = 0.f;
  if (c > 0) {
    xw0 = xin_[(rowbase + t0 - 3) * D_INNER + d];
    xw1 = xin_[(rowbase + t0 - 2) * D_INNER + d];
    xw2 = xin_[(rowbase + t0 - 1) * D_INNER + d];
  }
  float h = hstate[(size_t)c * (NCHAN * 16) + ch * 16 + n];
  const float* xr = xdbl + (rowbase + t0) * 96;
  for (int t = 0; t < CL; ++t, xr += 96) {
    const size_t row = rowbase + t0 + t;
    const float xw3 = xin_[row * D_INNER + d];
    float p = xr[n] * wdt0 + xr[n + 16] * wdt1 + xr[n + 32] * wdt2 + xr[n + 48] * wdt3;
    p += __shfl_xor(p, 1, 16);
    p += __shfl_xor(p, 2, 16);
    p += __shfl_xor(p, 4, 16);
    p += __shfl_xor(p, 8, 16);
    const float v = p + bdtv;
    const float dtv = (v > 20.f) ? v : log1pf(__expf(v));
    float xc = cbv + w0 * xw0 + w1 * xw1 + w2 * xw2 + w3 * xw3;
    xc = siluf(xc);
    const float Bv = xr[DT_RANK + n];
    const float Cv = xr[DT_RANK + D_STATE + n];
    h = __expf(dtv * A) * h + (dtv * xc) * Bv;
    float contrib = h * Cv;
    contrib += __shfl_xor(contrib, 1, 16);
    contrib += __shfl_xor(contrib, 2, 16);
    contrib += __shfl_xor(contrib, 4, 16);
    contrib += __shfl_xor(contrib, 8, 16);
    if (n == 0) {
      const size_t idx = row * D_INNER + d;
      zs[idx] = (contrib + Dv * xc) * zs[idx];
    }
    xw0 = xw1; xw1 = xw2; xw2 = xw3;
  }
}

extern "C" void kernel_launch(void* const* d_in, const int* in_sizes, int n_in,
                              void* d_out, int out_size, void* d_ws, size_t ws_size,
                              hipStream_t stream) {
  const float* x      = (const float*)d_in[0];
  const float* W_in   = (const float*)d_in[1];
  const float* conv_w = (const float*)d_in[2];
  const float* conv_b = (const float*)d_in[3];
  const float* W_x    = (const float*)d_in[4];
  const float* W_dt   = (const float*)d_in[5];
  const float* b_dt   = (const float*)d_in[6];
  const float* A_log  = (const float*)d_in[7];
  const float* Dp     = (const float*)d_in[8];
  const float* W_out  = (const float*)d_in[9];
  float* out = (float*)d_out;

  const size_t NE = (size_t)BL * D_INNER;        // 16.8M
  const size_t need = (2 * NE + (size_t)BL * 96) * sizeof(float);  // ~137 MB
  if (ws_size < need) {
    fill_kernel<<<dim3((out_size + 255) / 256), 256, 0, stream>>>(out, out_size, 1.0e9f);
    return;
  }

  float* ws      = (float*)d_ws;
  float* x_inner = ws;            // NE
  float* z_silu  = x_inner + NE;  // NE
  float* x_dbl   = z_silu + NE;   // BL*96

  // chunk-state scratch lives in d_out (written before final GEMM overwrites it)
  // hstate: NCH*NCHAN*16 = 4.19M floats; dtsum: NCH*NCHAN = 262K floats.
  // out_size = BL*D_MODEL = 8.39M floats -> fits.
  float* hstate = out;
  float* dtsum  = out + (size_t)NCH * NCHAN * 16;

  // 1) xz projection: split into x_inner / silu(z)
  gemm_att<1><<<dim3((4096 / 64) * (BL / 64)), 256, 0, stream>>>(
      x, W_in, x_inner, z_silu, BL, 2 * D_INNER, D_MODEL);

  // 2) x_dbl = conv_silu(x_inner) @ W_x^T
  gemm_xdbl_conv<<<dim3(BL / 32), 256, 0, stream>>>(
      x_inner, conv_w, conv_b, W_x, x_dbl);

  // 3) chunked scan
  scan_part1<<<dim3(NCH * 256), 256, 0, stream>>>(
      x_inner, x_dbl, conv_w, conv_b, W_dt, b_dt, A_log, hstate, dtsum);
  scan_part2<<<dim3((NCHAN * 16) / 256), 256, 0, stream>>>(A_log, hstate, dtsum);
  scan_part3<<<dim3(NCH * 256), 256, 0, stream>>>(
      x_inner, x_dbl, conv_w, conv_b, W_dt, b_dt, A_log, Dp, hstate, z_silu);

  // 4) out = (y * silu(z)) @ W_out^T
  gemm_att<0><<<dim3((D_MODEL / 64) * (BL / 64)), 256, 0, stream>>>(
      z_silu, W_out, out, nullptr, BL, D_MODEL, D_INNER);
}

// Round 4
// 2769.717 us; speedup vs baseline: 2.6992x; 1.5553x over previous
//
#include <hip/hip_runtime.h>
#include <math.h>

#define D_MODEL 1024
#define D_STATE 16
#define D_CONV  4
#define D_INNER 2048
#define DT_RANK 64
#define B_SZ    2
#define SEQ     4096
#define BL      (B_SZ*SEQ)   // 8192 rows
#define NCH     64           // time chunks
#define CL      (SEQ/NCH)    // 64 steps per chunk
#define NCHAN   (B_SZ*D_INNER)  // 4096 scan channels

typedef __attribute__((ext_vector_type(8))) short bf16x8;
typedef __attribute__((ext_vector_type(4))) float f32x4;

__device__ __forceinline__ float siluf(float v) { return v / (1.f + __expf(-v)); }

__device__ __forceinline__ unsigned short bf16_rn(float f) {
  unsigned int u = __float_as_uint(f);
  unsigned int r = u + 0x7FFFu + ((u >> 16) & 1u);
  return (unsigned short)(r >> 16);
}

__global__ __launch_bounds__(256) void fill_kernel(float* p, int n, float v) {
  int i = blockIdx.x * 256 + threadIdx.x;
  if (i < n) p[i] = v;
}

// C[M,N] = A[M,K] @ B[N,K]^T with split-bf16 (hi/lo) MFMA, f32-level accuracy.
// EPI==0: plain store. EPI==1: n < D_INNER -> C0 (x_inner), else C1 (silu(z)).
template <int EPI>
__global__ __launch_bounds__(256) void gemm_mfma(const float* __restrict__ A,
                                                 const float* __restrict__ B,
                                                 float* __restrict__ C0,
                                                 float* __restrict__ C1,
                                                 int M, int N, int K) {
  constexpr int BK = 32;
  constexpr int LDT = 40;            // padded LDS row stride (bf16 elems)
  __shared__ unsigned short Ah[128 * LDT], Al[128 * LDT];
  __shared__ unsigned short Bh[128 * LDT], Bl[128 * LDT];

  const int nblk = N >> 7;
  const int bx = blockIdx.x % nblk;
  const int by = blockIdx.x / nblk;
  const int m0 = by << 7, n0 = bx << 7;
  const int tid = threadIdx.x;
  const int lane = tid & 63;
  const int wave = tid >> 6;         // 0..3
  const int wr = wave >> 1, wc = wave & 1;
  const int lrow = lane & 15, lq = lane >> 4;

  f32x4 acc[4][4] = {};

  for (int k0 = 0; k0 < K; k0 += BK) {
    __syncthreads();
    // stage A-tile and B-tile: f32 -> hi/lo bf16
#pragma unroll
    for (int j = 0; j < 4; ++j) {
      const int idx = tid + j * 256;       // 0..1023 float4 slots
      const int r = idx >> 3, c4 = idx & 7;
      const float4 va = *(const float4*)&A[(size_t)(m0 + r) * K + k0 + c4 * 4];
      const float4 vb = *(const float4*)&B[(size_t)(n0 + r) * K + k0 + c4 * 4];
      unsigned short ah0 = bf16_rn(va.x), ah1 = bf16_rn(va.y), ah2 = bf16_rn(va.z), ah3 = bf16_rn(va.w);
      unsigned short bh0 = bf16_rn(vb.x), bh1 = bf16_rn(vb.y), bh2 = bf16_rn(vb.z), bh3 = bf16_rn(vb.w);
      float af0 = __uint_as_float((unsigned)ah0 << 16), af1 = __uint_as_float((unsigned)ah1 << 16);
      float af2 = __uint_as_float((unsigned)ah2 << 16), af3 = __uint_as_float((unsigned)ah3 << 16);
      float bf0 = __uint_as_float((unsigned)bh0 << 16), bf1 = __uint_as_float((unsigned)bh1 << 16);
      float bf2 = __uint_as_float((unsigned)bh2 << 16), bf3 = __uint_as_float((unsigned)bh3 << 16);
      *(ushort4*)&Ah[r * LDT + c4 * 4] = make_ushort4(ah0, ah1, ah2, ah3);
      *(ushort4*)&Al[r * LDT + c4 * 4] = make_ushort4(bf16_rn(va.x - af0), bf16_rn(va.y - af1),
                                                      bf16_rn(va.z - af2), bf16_rn(va.w - af3));
      *(ushort4*)&Bh[r * LDT + c4 * 4] = make_ushort4(bh0, bh1, bh2, bh3);
      *(ushort4*)&Bl[r * LDT + c4 * 4] = make_ushort4(bf16_rn(vb.x - bf0), bf16_rn(vb.y - bf1),
                                                      bf16_rn(vb.z - bf2), bf16_rn(vb.w - bf3));
    }
    __syncthreads();

    bf16x8 ah[4], al[4], bh[4], bl[4];
#pragma unroll
    for (int f = 0; f < 4; ++f) {
      const int ra = wr * 64 + f * 16 + lrow;
      const int rb = wc * 64 + f * 16 + lrow;
      ah[f] = *(const bf16x8*)&Ah[ra * LDT + lq * 8];
      al[f] = *(const bf16x8*)&Al[ra * LDT + lq * 8];
      bh[f] = *(const bf16x8*)&Bh[rb * LDT + lq * 8];
      bl[f] = *(const bf16x8*)&Bl[rb * LDT + lq * 8];
    }
#pragma unroll
    for (int fm = 0; fm < 4; ++fm)
#pragma unroll
      for (int fn = 0; fn < 4; ++fn) {
        acc[fm][fn] = __builtin_amdgcn_mfma_f32_16x16x32_bf16(ah[fm], bh[fn], acc[fm][fn], 0, 0, 0);
        acc[fm][fn] = __builtin_amdgcn_mfma_f32_16x16x32_bf16(ah[fm], bl[fn], acc[fm][fn], 0, 0, 0);
        acc[fm][fn] = __builtin_amdgcn_mfma_f32_16x16x32_bf16(al[fm], bh[fn], acc[fm][fn], 0, 0, 0);
      }
  }

#pragma unroll
  for (int fm = 0; fm < 4; ++fm)
#pragma unroll
    for (int fn = 0; fn < 4; ++fn)
#pragma unroll
      for (int r = 0; r < 4; ++r) {
        const int m = m0 + wr * 64 + fm * 16 + lq * 4 + r;
        const int n = n0 + wc * 64 + fn * 16 + lrow;
        const float v = acc[fm][fn][r];
        if (EPI == 0) {
          C0[(size_t)m * N + n] = v;
        } else {
          if (n < D_INNER)
            C0[(size_t)m * D_INNER + n] = v;
          else
            C1[(size_t)m * D_INNER + (n - D_INNER)] = siluf(v);
        }
      }
}

// x_dbl[BL,96] = conv_silu(x_inner)[BL,2048] @ W_x[96,2048]^T (conv fused)
__global__ __launch_bounds__(256) void gemm_xdbl_conv(const float* __restrict__ xin_,
                                                      const float* __restrict__ cw,
                                                      const float* __restrict__ cb,
                                                      const float* __restrict__ Bw,
                                                      float* __restrict__ C) {
  __shared__ float As[32][33];
  __shared__ float Bs[96][33];
  const int m0 = blockIdx.x * 32;
  const int tid = threadIdx.x;
  const int tx = tid & 15, ty = tid >> 4;
  float acc[2][6] = {};
  for (int k0 = 0; k0 < D_INNER; k0 += 32) {
#pragma unroll
    for (int j = 0; j < 4; ++j) {
      int i = tid + j * 256;
      int r = i >> 5, c = i & 31;
      int m = m0 + r;
      int d = k0 + c;
      int t = m & (SEQ - 1);
      float a = cb[d];
#pragma unroll
      for (int kk = 0; kk < D_CONV; ++kk) {
        int tt = t - (D_CONV - 1) + kk;
        if (tt >= 0) a += xin_[(size_t)(m - (D_CONV - 1) + kk) * D_INNER + d] * cw[d * D_CONV + kk];
      }
      As[r][c] = siluf(a);
    }
#pragma unroll
    for (int j = 0; j < 12; ++j) {
      int i = tid + j * 256;
      int r = i >> 5, c = i & 31;
      Bs[r][c] = Bw[(size_t)r * D_INNER + k0 + c];
    }
    __syncthreads();
#pragma unroll
    for (int k = 0; k < 32; ++k) {
#pragma unroll
      for (int rr = 0; rr < 2; ++rr) {
        float a = As[ty * 2 + rr][k];
#pragma unroll
        for (int j = 0; j < 6; ++j) acc[rr][j] += a * Bs[tx * 6 + j][k];
      }
    }
    __syncthreads();
  }
#pragma unroll
  for (int rr = 0; rr < 2; ++rr)
#pragma unroll
    for (int j = 0; j < 6; ++j)
      C[(size_t)(m0 + ty * 2 + rr) * 96 + tx * 6 + j] = acc[rr][j];
}

// ---- chunked selective scan ----
__global__ __launch_bounds__(256) void scan_part1(const float* __restrict__ xin_,
                                                  const float* __restrict__ xdbl,
                                                  const float* __restrict__ cw,
                                                  const float* __restrict__ cb,
                                                  const float* __restrict__ Wdt,
                                                  const float* __restrict__ bdt,
                                                  const float* __restrict__ Alog,
                                                  float* __restrict__ hstate,
                                                  float* __restrict__ dtsum) {
  const int tid = threadIdx.x;
  const int n = tid & 15;
  const int g = blockIdx.x & 255;
  const int c = blockIdx.x >> 8;
  const int ch = g * 16 + (tid >> 4);
  const int b = ch >> 11;
  const int d = ch & (D_INNER - 1);

  const float A = -__expf(Alog[d * D_STATE + n]);
  const float w0 = cw[d * D_CONV + 0], w1 = cw[d * D_CONV + 1];
  const float w2 = cw[d * D_CONV + 2], w3 = cw[d * D_CONV + 3];
  const float cbv = cb[d];
  const float bdtv = bdt[d];
  const float wdt0 = Wdt[(size_t)d * DT_RANK + n];
  const float wdt1 = Wdt[(size_t)d * DT_RANK + n + 16];
  const float wdt2 = Wdt[(size_t)d * DT_RANK + n + 32];
  const float wdt3 = Wdt[(size_t)d * DT_RANK + n + 48];

  const size_t rowbase = (size_t)b * SEQ;
  const int t0 = c * CL;
  float xw0 = 0.f, xw1 = 0.f, xw2 = 0.f;
  if (c > 0) {
    xw0 = xin_[(rowbase + t0 - 3) * D_INNER + d];
    xw1 = xin_[(rowbase + t0 - 2) * D_INNER + d];
    xw2 = xin_[(rowbase + t0 - 1) * D_INNER + d];
  }
  float h = 0.f, ds = 0.f;
  const float* xr = xdbl + (rowbase + t0) * 96;
  for (int t = 0; t < CL; ++t, xr += 96) {
    const float xw3 = xin_[(rowbase + t0 + t) * D_INNER + d];
    float p = xr[n] * wdt0 + xr[n + 16] * wdt1 + xr[n + 32] * wdt2 + xr[n + 48] * wdt3;
    p += __shfl_xor(p, 1, 16);
    p += __shfl_xor(p, 2, 16);
    p += __shfl_xor(p, 4, 16);
    p += __shfl_xor(p, 8, 16);
    const float v = p + bdtv;
    const float dtv = (v > 20.f) ? v : log1pf(__expf(v));
    float xc = cbv + w0 * xw0 + w1 * xw1 + w2 * xw2 + w3 * xw3;
    xc = siluf(xc);
    const float Bv = xr[DT_RANK + n];
    h = __expf(dtv * A) * h + (dtv * xc) * Bv;
    ds += dtv;
    xw0 = xw1; xw1 = xw2; xw2 = xw3;
  }
  hstate[(size_t)c * (NCHAN * 16) + ch * 16 + n] = h;
  if (n == 0) dtsum[c * NCHAN + ch] = ds;
}

__global__ __launch_bounds__(256) void scan_part2(const float* __restrict__ Alog,
                                                  float* __restrict__ hstate,
                                                  const float* __restrict__ dtsum) {
  const int idx = blockIdx.x * 256 + threadIdx.x;
  const int n = idx & 15;
  const int ch = idx >> 4;
  const int d = ch & (D_INNER - 1);
  const float A = -__expf(Alog[d * D_STATE + n]);
  float H = 0.f;
  for (int c = 0; c < NCH; ++c) {
    const size_t off = (size_t)c * (NCHAN * 16) + idx;
    const float hf = hstate[off];
    const float s = dtsum[c * NCHAN + ch];
    const float Ap = __expf(A * s);
    hstate[off] = H;
    H = Ap * H + hf;
  }
}

__global__ __launch_bounds__(256) void scan_part3(const float* __restrict__ xin_,
                                                  const float* __restrict__ xdbl,
                                                  const float* __restrict__ cw,
                                                  const float* __restrict__ cb,
                                                  const float* __restrict__ Wdt,
                                                  const float* __restrict__ bdt,
                                                  const float* __restrict__ Alog,
                                                  const float* __restrict__ Dp,
                                                  const float* __restrict__ hstate,
                                                  float* __restrict__ zs) {
  const int tid = threadIdx.x;
  const int n = tid & 15;
  const int g = blockIdx.x & 255;
  const int c = blockIdx.x >> 8;
  const int ch = g * 16 + (tid >> 4);
  const int b = ch >> 11;
  const int d = ch & (D_INNER - 1);

  const float A = -__expf(Alog[d * D_STATE + n]);
  const float Dv = Dp[d];
  const float w0 = cw[d * D_CONV + 0], w1 = cw[d * D_CONV + 1];
  const float w2 = cw[d * D_CONV + 2], w3 = cw[d * D_CONV + 3];
  const float cbv = cb[d];
  const float bdtv = bdt[d];
  const float wdt0 = Wdt[(size_t)d * DT_RANK + n];
  const float wdt1 = Wdt[(size_t)d * DT_RANK + n + 16];
  const float wdt2 = Wdt[(size_t)d * DT_RANK + n + 32];
  const float wdt3 = Wdt[(size_t)d * DT_RANK + n + 48];

  const size_t rowbase = (size_t)b * SEQ;
  const int t0 = c * CL;
  float xw0 = 0.f, xw1 = 0.f, xw2 = 0.f;
  if (c > 0) {
    xw0 = xin_[(rowbase + t0 - 3) * D_INNER + d];
    xw1 = xin_[(rowbase + t0 - 2) * D_INNER + d];
    xw2 = xin_[(rowbase + t0 - 1) * D_INNER + d];
  }
  float h = hstate[(size_t)c * (NCHAN * 16) + ch * 16 + n];
  const float* xr = xdbl + (rowbase + t0) * 96;
  for (int t = 0; t < CL; ++t, xr += 96) {
    const size_t row = rowbase + t0 + t;
    const float xw3 = xin_[row * D_INNER + d];
    float p = xr[n] * wdt0 + xr[n + 16] * wdt1 + xr[n + 32] * wdt2 + xr[n + 48] * wdt3;
    p += __shfl_xor(p, 1, 16);
    p += __shfl_xor(p, 2, 16);
    p += __shfl_xor(p, 4, 16);
    p += __shfl_xor(p, 8, 16);
    const float v = p + bdtv;
    const float dtv = (v > 20.f) ? v : log1pf(__expf(v));
    float xc = cbv + w0 * xw0 + w1 * xw1 + w2 * xw2 + w3 * xw3;
    xc = siluf(xc);
    const float Bv = xr[DT_RANK + n];
    const float Cv = xr[DT_RANK + D_STATE + n];
    h = __expf(dtv * A) * h + (dtv * xc) * Bv;
    float contrib = h * Cv;
    contrib += __shfl_xor(contrib, 1, 16);
    contrib += __shfl_xor(contrib, 2, 16);
    contrib += __shfl_xor(contrib, 4, 16);
    contrib += __shfl_xor(contrib, 8, 16);
    if (n == 0) {
      const size_t idx = row * D_INNER + d;
      zs[idx] = (contrib + Dv * xc) * zs[idx];
    }
    xw0 = xw1; xw1 = xw2; xw2 = xw3;
  }
}

extern "C" void kernel_launch(void* const* d_in, const int* in_sizes, int n_in,
                              void* d_out, int out_size, void* d_ws, size_t ws_size,
                              hipStream_t stream) {
  const float* x      = (const float*)d_in[0];
  const float* W_in   = (const float*)d_in[1];
  const float* conv_w = (const float*)d_in[2];
  const float* conv_b = (const float*)d_in[3];
  const float* W_x    = (const float*)d_in[4];
  const float* W_dt   = (const float*)d_in[5];
  const float* b_dt   = (const float*)d_in[6];
  const float* A_log  = (const float*)d_in[7];
  const float* Dp     = (const float*)d_in[8];
  const float* W_out  = (const float*)d_in[9];
  float* out = (float*)d_out;

  const size_t NE = (size_t)BL * D_INNER;
  const size_t need = (2 * NE + (size_t)BL * 96) * sizeof(float);  // ~137 MB
  if (ws_size < need) {
    fill_kernel<<<dim3((out_size + 255) / 256), 256, 0, stream>>>(out, out_size, 1.0e9f);
    return;
  }

  float* ws      = (float*)d_ws;
  float* x_inner = ws;            // NE
  float* z_silu  = x_inner + NE;  // NE
  float* x_dbl   = z_silu + NE;   // BL*96

  // chunk-state scratch in d_out (dead before final GEMM writes it)
  float* hstate = out;
  float* dtsum  = out + (size_t)NCH * NCHAN * 16;

  // 1) xz projection (split-bf16 MFMA): split into x_inner / silu(z)
  gemm_mfma<1><<<dim3((4096 / 128) * (BL / 128)), 256, 0, stream>>>(
      x, W_in, x_inner, z_silu, BL, 2 * D_INNER, D_MODEL);

  // 2) x_dbl = conv_silu(x_inner) @ W_x^T
  gemm_xdbl_conv<<<dim3(BL / 32), 256, 0, stream>>>(
      x_inner, conv_w, conv_b, W_x, x_dbl);

  // 3) chunked scan
  scan_part1<<<dim3(NCH * 256), 256, 0, stream>>>(
      x_inner, x_dbl, conv_w, conv_b, W_dt, b_dt, A_log, hstate, dtsum);
  scan_part2<<<dim3((NCHAN * 16) / 256), 256, 0, stream>>>(A_log, hstate, dtsum);
  scan_part3<<<dim3(NCH * 256), 256, 0, stream>>>(
      x_inner, x_dbl, conv_w, conv_b, W_dt, b_dt, A_log, Dp, hstate, z_silu);

  // 4) out = (y * silu(z)) @ W_out^T (split-bf16 MFMA)
  gemm_mfma<0><<<dim3((D_MODEL / 128) * (BL / 128)), 256, 0, stream>>>(
      z_silu, W_out, out, nullptr, BL, D_MODEL, D_INNER);
}

// Round 5
// 2180.075 us; speedup vs baseline: 3.4292x; 1.2705x over previous
//
#include <hip/hip_runtime.h>
#include <math.h>

#define D_MODEL 1024
#define D_STATE 16
#define D_CONV  4
#define D_INNER 2048
#define DT_RANK 64
#define B_SZ    2
#define SEQ     4096
#define BL      (B_SZ*SEQ)   // 8192 rows
#define NCH     64           // time chunks
#define CL      (SEQ/NCH)    // 64 steps per chunk
#define NCHAN   (B_SZ*D_INNER)  // 4096 scan channels
#define L2E     1.4426950408889634f

typedef __attribute__((ext_vector_type(8))) short bf16x8;
typedef __attribute__((ext_vector_type(4))) float f32x4;

__device__ __forceinline__ float silu_fast(float v) {
  const float e = exp2f(v * (-L2E));
  return v * __builtin_amdgcn_rcpf(1.f + e);
}

__device__ __forceinline__ float softplus_fast(float v) {
  const float e = exp2f(fabsf(v) * (-L2E));
  return fmaxf(v, 0.f) + __logf(1.f + e);
}

__device__ __forceinline__ unsigned short bf16_rn(float f) {
  unsigned int u = __float_as_uint(f);
  unsigned int r = u + 0x7FFFu + ((u >> 16) & 1u);
  return (unsigned short)(r >> 16);
}

__global__ __launch_bounds__(256) void fill_kernel(float* p, int n, float v) {
  int i = blockIdx.x * 256 + threadIdx.x;
  if (i < n) p[i] = v;
}

// C[M,N] = A[M,K] @ B[N,K]^T with split-bf16 (hi/lo) MFMA, f32-level accuracy.
template <int EPI>
__global__ __launch_bounds__(256) void gemm_mfma(const float* __restrict__ A,
                                                 const float* __restrict__ B,
                                                 float* __restrict__ C0,
                                                 float* __restrict__ C1,
                                                 int M, int N, int K) {
  constexpr int BK = 32;
  constexpr int LDT = 40;
  __shared__ unsigned short Ah[128 * LDT], Al[128 * LDT];
  __shared__ unsigned short Bh[128 * LDT], Bl[128 * LDT];

  const int nblk = N >> 7;
  const int bx = blockIdx.x % nblk;
  const int by = blockIdx.x / nblk;
  const int m0 = by << 7, n0 = bx << 7;
  const int tid = threadIdx.x;
  const int lane = tid & 63;
  const int wave = tid >> 6;
  const int wr = wave >> 1, wc = wave & 1;
  const int lrow = lane & 15, lq = lane >> 4;

  f32x4 acc[4][4] = {};

  for (int k0 = 0; k0 < K; k0 += BK) {
    __syncthreads();
#pragma unroll
    for (int j = 0; j < 4; ++j) {
      const int idx = tid + j * 256;
      const int r = idx >> 3, c4 = idx & 7;
      const float4 va = *(const float4*)&A[(size_t)(m0 + r) * K + k0 + c4 * 4];
      const float4 vb = *(const float4*)&B[(size_t)(n0 + r) * K + k0 + c4 * 4];
      unsigned short ah0 = bf16_rn(va.x), ah1 = bf16_rn(va.y), ah2 = bf16_rn(va.z), ah3 = bf16_rn(va.w);
      unsigned short bh0 = bf16_rn(vb.x), bh1 = bf16_rn(vb.y), bh2 = bf16_rn(vb.z), bh3 = bf16_rn(vb.w);
      float af0 = __uint_as_float((unsigned)ah0 << 16), af1 = __uint_as_float((unsigned)ah1 << 16);
      float af2 = __uint_as_float((unsigned)ah2 << 16), af3 = __uint_as_float((unsigned)ah3 << 16);
      float bf0 = __uint_as_float((unsigned)bh0 << 16), bf1 = __uint_as_float((unsigned)bh1 << 16);
      float bf2 = __uint_as_float((unsigned)bh2 << 16), bf3 = __uint_as_float((unsigned)bh3 << 16);
      *(ushort4*)&Ah[r * LDT + c4 * 4] = make_ushort4(ah0, ah1, ah2, ah3);
      *(ushort4*)&Al[r * LDT + c4 * 4] = make_ushort4(bf16_rn(va.x - af0), bf16_rn(va.y - af1),
                                                      bf16_rn(va.z - af2), bf16_rn(va.w - af3));
      *(ushort4*)&Bh[r * LDT + c4 * 4] = make_ushort4(bh0, bh1, bh2, bh3);
      *(ushort4*)&Bl[r * LDT + c4 * 4] = make_ushort4(bf16_rn(vb.x - bf0), bf16_rn(vb.y - bf1),
                                                      bf16_rn(vb.z - bf2), bf16_rn(vb.w - bf3));
    }
    __syncthreads();

    bf16x8 ah[4], al[4], bh[4], bl[4];
#pragma unroll
    for (int f = 0; f < 4; ++f) {
      const int ra = wr * 64 + f * 16 + lrow;
      const int rb = wc * 64 + f * 16 + lrow;
      ah[f] = *(const bf16x8*)&Ah[ra * LDT + lq * 8];
      al[f] = *(const bf16x8*)&Al[ra * LDT + lq * 8];
      bh[f] = *(const bf16x8*)&Bh[rb * LDT + lq * 8];
      bl[f] = *(const bf16x8*)&Bl[rb * LDT + lq * 8];
    }
#pragma unroll
    for (int fm = 0; fm < 4; ++fm)
#pragma unroll
      for (int fn = 0; fn < 4; ++fn) {
        acc[fm][fn] = __builtin_amdgcn_mfma_f32_16x16x32_bf16(ah[fm], bh[fn], acc[fm][fn], 0, 0, 0);
        acc[fm][fn] = __builtin_amdgcn_mfma_f32_16x16x32_bf16(ah[fm], bl[fn], acc[fm][fn], 0, 0, 0);
        acc[fm][fn] = __builtin_amdgcn_mfma_f32_16x16x32_bf16(al[fm], bh[fn], acc[fm][fn], 0, 0, 0);
      }
  }

#pragma unroll
  for (int fm = 0; fm < 4; ++fm)
#pragma unroll
    for (int fn = 0; fn < 4; ++fn)
#pragma unroll
      for (int r = 0; r < 4; ++r) {
        const int m = m0 + wr * 64 + fm * 16 + lq * 4 + r;
        const int n = n0 + wc * 64 + fn * 16 + lrow;
        const float v = acc[fm][fn][r];
        if (EPI == 0) {
          C0[(size_t)m * N + n] = v;
        } else {
          if (n < D_INNER)
            C0[(size_t)m * D_INNER + n] = v;
          else
            C1[(size_t)m * D_INNER + (n - D_INNER)] = silu_fast(v);
        }
      }
}

// x_dbl[BL,96] = conv_silu(x_inner)[BL,2048] @ W_x[96,2048]^T (conv fused)
__global__ __launch_bounds__(256) void gemm_xdbl_conv(const float* __restrict__ xin_,
                                                      const float* __restrict__ cw,
                                                      const float* __restrict__ cb,
                                                      const float* __restrict__ Bw,
                                                      float* __restrict__ C) {
  __shared__ float As[32][33];
  __shared__ float Bs[96][33];
  const int m0 = blockIdx.x * 32;
  const int tid = threadIdx.x;
  const int tx = tid & 15, ty = tid >> 4;
  float acc[2][6] = {};
  for (int k0 = 0; k0 < D_INNER; k0 += 32) {
#pragma unroll
    for (int j = 0; j < 4; ++j) {
      int i = tid + j * 256;
      int r = i >> 5, c = i & 31;
      int m = m0 + r;
      int d = k0 + c;
      int t = m & (SEQ - 1);
      float a = cb[d];
#pragma unroll
      for (int kk = 0; kk < D_CONV; ++kk) {
        int tt = t - (D_CONV - 1) + kk;
        if (tt >= 0) a += xin_[(size_t)(m - (D_CONV - 1) + kk) * D_INNER + d] * cw[d * D_CONV + kk];
      }
      As[r][c] = silu_fast(a);
    }
#pragma unroll
    for (int j = 0; j < 12; ++j) {
      int i = tid + j * 256;
      int r = i >> 5, c = i & 31;
      Bs[r][c] = Bw[(size_t)r * D_INNER + k0 + c];
    }
    __syncthreads();
#pragma unroll
    for (int k = 0; k < 32; ++k) {
#pragma unroll
      for (int rr = 0; rr < 2; ++rr) {
        float a = As[ty * 2 + rr][k];
#pragma unroll
        for (int j = 0; j < 6; ++j) acc[rr][j] += a * Bs[tx * 6 + j][k];
      }
    }
    __syncthreads();
  }
#pragma unroll
  for (int rr = 0; rr < 2; ++rr)
#pragma unroll
    for (int j = 0; j < 6; ++j)
      C[(size_t)(m0 + ty * 2 + rr) * 96 + tx * 6 + j] = acc[rr][j];
}

// ---- chunked selective scan, phase-parallel ----
// Block = 16 channels x 16 lanes. Lane j doubles as: state index j for the
// recurrence, and step index j within each 16-step phase for dt/conv/silu.
// PASS 1: h from 0 -> hstate final + dtsum.  PASS 3: h seeded; y -> zs *= y.
template <int PASS>
__global__ __launch_bounds__(256) void scan_chunk(const float* __restrict__ xin_,
                                                  const float* __restrict__ xdbl,
                                                  const float* __restrict__ cw,
                                                  const float* __restrict__ cb,
                                                  const float* __restrict__ Wdt,
                                                  const float* __restrict__ bdt,
                                                  const float* __restrict__ Alog,
                                                  const float* __restrict__ Dp,
                                                  float* __restrict__ hstate,
                                                  float* __restrict__ dtsum,
                                                  float* __restrict__ zs) {
  __shared__ float WdtS[16][64];
  const int tid = threadIdx.x;
  const int j = tid & 15;          // state idx AND phase-step idx
  const int q = tid >> 4;          // channel within block
  const int g = blockIdx.x & 255;  // channel group
  const int c = blockIdx.x >> 8;   // chunk
  const int ch = g * 16 + q;
  const int b = ch >> 11;
  const int d = ch & (D_INNER - 1);

  // stage W_dt rows for this block's 16 channels
  *(float4*)&WdtS[q][j * 4] = *(const float4*)&Wdt[(size_t)d * DT_RANK + j * 4];
  __syncthreads();

  const float A2 = -__expf(Alog[d * D_STATE + j]) * L2E;
  const float4 wv4 = *(const float4*)&cw[d * D_CONV];
  const float cbv = cb[d];
  const float bdtv = bdt[d];
  float Dv = 0.f;
  if (PASS == 3) Dv = Dp[d];
  const size_t rowbase = (size_t)b * SEQ;
  const int t0 = c * CL;

  float h;
  if (PASS == 1) h = 0.f;
  else h = hstate[(size_t)c * (NCHAN * 16) + ch * 16 + j];
  float dsacc = 0.f;

  for (int ph = 0; ph < 4; ++ph) {
    const int tj = t0 + ph * 16 + j;          // this lane's step
    const size_t row_j = rowbase + tj;

    // conv + silu for step tj (computed once, in parallel over lanes)
    float xacc = cbv;
#pragma unroll
    for (int kk = 0; kk < 4; ++kk) {
      const int tt = tj - 3 + kk;
      float xv = 0.f;
      if (tt >= 0) xv = xin_[(rowbase + tt) * D_INNER + d];
      xacc = fmaf(kk == 0 ? wv4.x : kk == 1 ? wv4.y : kk == 2 ? wv4.z : wv4.w, xv, xacc);
    }
    const float xcj = silu_fast(xacc);

    // dt for step tj: 64-wide dot vs LDS-staged W_dt row
    float p = bdtv;
    const float* xr = xdbl + row_j * 96;
#pragma unroll
    for (int kk = 0; kk < 16; ++kk) {
      const float4 xv = *(const float4*)(xr + kk * 4);
      const float4 wv = *(const float4*)&WdtS[q][kk * 4];
      p = fmaf(xv.x, wv.x, p); p = fmaf(xv.y, wv.y, p);
      p = fmaf(xv.z, wv.z, p); p = fmaf(xv.w, wv.w, p);
    }
    const float dtvj = softplus_fast(p);
    const float kj = dtvj * xcj;
    if (PASS == 1) dsacc += dtvj;

    // preload B (and C) for the 16 steps of this phase (state layout: lane j)
    float B_r[16], C_r[16];
#pragma unroll
    for (int s = 0; s < 16; ++s) {
      const size_t rr = (rowbase + t0 + ph * 16 + s) * 96;
      B_r[s] = xdbl[rr + DT_RANK + j];
      if (PASS == 3) C_r[s] = xdbl[rr + DT_RANK + D_STATE + j];
    }

    float ymine = 0.f;
#pragma unroll
    for (int s = 0; s < 16; ++s) {
      const float dtv_s = __shfl(dtvj, s, 16);
      const float k_s = __shfl(kj, s, 16);
      const float ab = exp2f(dtv_s * A2);
      h = fmaf(ab, h, k_s * B_r[s]);
      if (PASS == 3) {
        float cb_ = h * C_r[s];
        cb_ += __shfl_xor(cb_, 1, 16);
        cb_ += __shfl_xor(cb_, 2, 16);
        cb_ += __shfl_xor(cb_, 4, 16);
        cb_ += __shfl_xor(cb_, 8, 16);
        if (j == s) ymine = cb_;   // lane j keeps y for its own step
      }
    }
    if (PASS == 3) {
      const size_t idx = row_j * D_INNER + d;
      const float yv = ymine + Dv * xcj;
      zs[idx] = yv * zs[idx];
    }
  }

  if (PASS == 1) {
    hstate[(size_t)c * (NCHAN * 16) + ch * 16 + j] = h;
    dsacc += __shfl_xor(dsacc, 1, 16);
    dsacc += __shfl_xor(dsacc, 2, 16);
    dsacc += __shfl_xor(dsacc, 4, 16);
    dsacc += __shfl_xor(dsacc, 8, 16);
    if (j == 0) dtsum[c * NCHAN + ch] = dsacc;
  }
}

// Pass 2: sequential over chunks; converts h_loc_final -> H_in (in place).
__global__ __launch_bounds__(256) void scan_part2(const float* __restrict__ Alog,
                                                  float* __restrict__ hstate,
                                                  const float* __restrict__ dtsum) {
  const int idx = blockIdx.x * 256 + threadIdx.x;
  const int n = idx & 15;
  const int ch = idx >> 4;
  const int d = ch & (D_INNER - 1);
  const float A2 = -__expf(Alog[d * D_STATE + n]) * L2E;
  float H = 0.f;
  for (int c = 0; c < NCH; ++c) {
    const size_t off = (size_t)c * (NCHAN * 16) + idx;
    const float hf = hstate[off];
    const float s = dtsum[c * NCHAN + ch];
    const float Ap = exp2f(A2 * s);
    hstate[off] = H;
    H = fmaf(Ap, H, hf);
  }
}

extern "C" void kernel_launch(void* const* d_in, const int* in_sizes, int n_in,
                              void* d_out, int out_size, void* d_ws, size_t ws_size,
                              hipStream_t stream) {
  const float* x      = (const float*)d_in[0];
  const float* W_in   = (const float*)d_in[1];
  const float* conv_w = (const float*)d_in[2];
  const float* conv_b = (const float*)d_in[3];
  const float* W_x    = (const float*)d_in[4];
  const float* W_dt   = (const float*)d_in[5];
  const float* b_dt   = (const float*)d_in[6];
  const float* A_log  = (const float*)d_in[7];
  const float* Dp     = (const float*)d_in[8];
  const float* W_out  = (const float*)d_in[9];
  float* out = (float*)d_out;

  const size_t NE = (size_t)BL * D_INNER;
  const size_t need = (2 * NE + (size_t)BL * 96) * sizeof(float);  // ~137 MB
  if (ws_size < need) {
    fill_kernel<<<dim3((out_size + 255) / 256), 256, 0, stream>>>(out, out_size, 1.0e9f);
    return;
  }

  float* ws      = (float*)d_ws;
  float* x_inner = ws;            // NE
  float* z_silu  = x_inner + NE;  // NE
  float* x_dbl   = z_silu + NE;   // BL*96

  // chunk-state scratch in d_out (dead before final GEMM writes it)
  float* hstate = out;
  float* dtsum  = out + (size_t)NCH * NCHAN * 16;

  // 1) xz projection (split-bf16 MFMA): split into x_inner / silu(z)
  gemm_mfma<1><<<dim3((4096 / 128) * (BL / 128)), 256, 0, stream>>>(
      x, W_in, x_inner, z_silu, BL, 2 * D_INNER, D_MODEL);

  // 2) x_dbl = conv_silu(x_inner) @ W_x^T
  gemm_xdbl_conv<<<dim3(BL / 32), 256, 0, stream>>>(
      x_inner, conv_w, conv_b, W_x, x_dbl);

  // 3) chunked scan (phase-parallel)
  scan_chunk<1><<<dim3(NCH * 256), 256, 0, stream>>>(
      x_inner, x_dbl, conv_w, conv_b, W_dt, b_dt, A_log, Dp, hstate, dtsum, z_silu);
  scan_part2<<<dim3((NCHAN * 16) / 256), 256, 0, stream>>>(A_log, hstate, dtsum);
  scan_chunk<3><<<dim3(NCH * 256), 256, 0, stream>>>(
      x_inner, x_dbl, conv_w, conv_b, W_dt, b_dt, A_log, Dp, hstate, dtsum, z_silu);

  // 4) out = (y * silu(z)) @ W_out^T (split-bf16 MFMA)
  gemm_mfma<0><<<dim3((D_MODEL / 128) * (BL / 128)), 256, 0, stream>>>(
      z_silu, W_out, out, nullptr, BL, D_MODEL, D_INNER);
}